// Round 9
// baseline (1220.893 us; speedup 1.0000x reference)
//
#include <hip/hip_runtime.h>

// ---------------- problem dims ----------------
#define IN_F  128
#define GHID  512
#define NHID  128
#define NTOK  196608L   // 1024 * 192
#define LDSP  520       // LDS row pitch in bf16 elems (512 + 8 pad)

#define L2E 1.4426950408889634f

typedef __attribute__((ext_vector_type(8)))  short short8;
typedef __attribute__((ext_vector_type(16))) float floatx16;
typedef __attribute__((ext_vector_type(4)))  float f4;

// ---------------- ws layout ----------------
// bf16 packed weights (ushort elems), 32x32x16 fragment order:
//   frag index = ((gate*(H/32) + tn) * (K/16) + tk), 512 elems per frag,
//   elem (lane,j): n = tn*32 + (lane&31), k = tk*16 + (lane>>5)*8 + j
#define O_GW0 0L
#define O_GW1 196608L
#define O_GW2 983040L
#define O_NW0 1769472L
#define O_NW1 1818624L
#define NWS   1867776L
// fp32 region (float elems), base byte = NWS*2
#define F_GB0 0
#define F_GB1 1536
#define F_GB2 3072
#define F_NB0 4608
#define F_NB1 4992
#define F_WE  5376
#define F_AW  5888
#define F_BE  6016
#define F_AB  6017

__device__ __forceinline__ unsigned short f2bf(float f) {
  unsigned int u = __float_as_uint(f);
  u += 0x7fffu + ((u >> 16) & 1u);      // RNE
  return (unsigned short)(u >> 16);
}

// ---------------- prep kernel: repack weights (NO prescale — R6 lesson) ----
__device__ __forceinline__ long srcoff(long pp, int H, int K) {
  long f = pp >> 9;
  int r = (int)(pp & 511);
  int ln = r >> 3, j = r & 7;
  int nKT = K >> 4, nCT = H >> 5;       // 32x32x16 tiling
  int tk = (int)(f % nKT);
  long t2 = f / nKT;
  int tn = (int)(t2 % nCT);
  int gate = (int)(t2 / nCT);
  int n = tn * 32 + (ln & 31);
  int k = tk * 16 + ((ln >> 5) << 3) + j;
  int go = (gate == 0) ? 0 : ((gate == 1) ? 2 * H : 3 * H);  // i, c, o rows
  return (long)(go + n) * K + k;
}

__global__ void prep_kernel(
    const float* __restrict__ gW0, const float* __restrict__ gbi0, const float* __restrict__ gbh0,
    const float* __restrict__ gW,  const float* __restrict__ gbi,  const float* __restrict__ gbh,
    const float* __restrict__ eW,  const float* __restrict__ eb,
    const float* __restrict__ nW0, const float* __restrict__ nbi0, const float* __restrict__ nbh0,
    const float* __restrict__ nW,  const float* __restrict__ nbi,  const float* __restrict__ nbh,
    const float* __restrict__ aW,  const float* __restrict__ ab,
    unsigned short* __restrict__ wpk, float* __restrict__ fpk)
{
  long idx = (long)blockIdx.x * blockDim.x + threadIdx.x;
  if (idx < NWS) {
    const float* src;
    long off;
    if (idx < O_GW1)      { off = srcoff(idx - O_GW0, 512, 128); src = gW0; }
    else if (idx < O_GW2) { off = srcoff(idx - O_GW1, 512, 512); src = gW; }
    else if (idx < O_NW0) { off = srcoff(idx - O_GW2, 512, 512); src = gW + 1048576; }
    else if (idx < O_NW1) { off = srcoff(idx - O_NW0, 128, 128); src = nW0; }
    else                  { off = srcoff(idx - O_NW1, 128, 128); src = nW; }
    wpk[idx] = f2bf(src[off]);
    return;
  }
  long p = idx - NWS;
  if (p < 1536) { int g = (int)(p >> 9), n = (int)(p & 511);
    int o = (g == 0 ? 0 : (g == 1 ? 1024 : 1536)) + n;
    fpk[F_GB0 + p] = gbi0[o] + gbh0[o]; return; }
  p -= 1536;
  if (p < 1536) { int g = (int)(p >> 9), n = (int)(p & 511);
    int o = (g == 0 ? 0 : (g == 1 ? 1024 : 1536)) + n;
    fpk[F_GB1 + p] = gbi[o] + gbh[o]; return; }
  p -= 1536;
  if (p < 1536) { int g = (int)(p >> 9), n = (int)(p & 511);
    int o = (g == 0 ? 0 : (g == 1 ? 1024 : 1536)) + n;
    fpk[F_GB2 + p] = gbi[2048 + o] + gbh[2048 + o]; return; }
  p -= 1536;
  if (p < 384) { int g = (int)(p / 128), n = (int)(p % 128);
    int o = (g == 0 ? 0 : (g == 1 ? 256 : 384)) + n;
    fpk[F_NB0 + p] = nbi0[o] + nbh0[o]; return; }
  p -= 384;
  if (p < 384) { int g = (int)(p / 128), n = (int)(p % 128);
    int o = (g == 0 ? 0 : (g == 1 ? 256 : 384)) + n;
    fpk[F_NB1 + p] = nbi[o] + nbh[o]; return; }
  p -= 384;
  if (p < 512) { float s = 0.f;
    for (int f = 0; f < 10; ++f) s += eW[f * 512 + p];
    fpk[F_WE + p] = s; return; }
  p -= 512;
  if (p < 128) { fpk[F_AW + p] = aW[p]; return; }
  p -= 128;
  if (p == 0) { float s = 0.f; for (int f = 0; f < 10; ++f) s += eb[f]; fpk[F_BE] = s; return; }
  if (p == 1) { fpk[F_AB] = ab[0]; return; }
}

// LSTM-cell combine from RAW gates (in-kernel scaling; prep stays byte-stable)
__device__ __forceinline__ float cell_h(float gi, float gc, float go) {
  float ei = __builtin_amdgcn_exp2f(gi * -L2E);
  float u  = __builtin_amdgcn_exp2f(gc * (2.0f * L2E));
  float eo = __builtin_amdgcn_exp2f(go * -L2E);
  float r1 = __builtin_amdgcn_rcpf((u + 1.f) * (1.f + ei));
  float cc = (u - 1.f) * r1;
  float s  = cc * cc;
  float num = cc * fmaf(10.f, s, 105.f);
  float den = fmaf(s, s + 45.f, 105.f);
  return num * __builtin_amdgcn_rcpf(den * (1.f + eo));
}

// ---------------- fused main kernel (32x32x16 MFMA) ----------------
// C/D layout (m74/m101-verified): col = lane&31, row = (reg&3)+8*(reg>>2)+4*(lane>>5).
// A: row = lane&31, k = (lane>>5)*8+j.  B: n = lane&31, k = (lane>>5)*8+j.
// RT row-tiles of 32 tokens per cp pass (B read once, applied to both).
// B-prefetch rotation hides L2 latency (R8).
template <int K, int H, int RT, int CPW, int NW, int MODE>
__device__ __forceinline__ void layer_run(
    const unsigned short* __restrict__ sIn,
    unsigned short* __restrict__ sOut,
    const unsigned short* __restrict__ wp,
    const float* __restrict__ bias,
    const float* __restrict__ dotw,
    float* accVec,
    int colTile0, int rtBase, int lane)
{
  constexpr int nKT = K / 16;
  constexpr int nCT = H / 32;
#pragma unroll
  for (int cp = 0; cp < CPW; ++cp) {
    int tn = colTile0 + cp * NW;
    int colg = tn * 32 + (lane & 31);
    const unsigned short* p0 = wp + (size_t)tn * nKT * 512 + lane * 8;
    const unsigned short* p1 = p0 + (size_t)nCT * nKT * 512;
    const unsigned short* p2 = p1 + (size_t)nCT * nKT * 512;
    short8 b0 = *(const short8*)(p0);
    short8 b1 = *(const short8*)(p1);
    short8 b2 = *(const short8*)(p2);
    float bi = bias[colg], bc = bias[H + colg], bo = bias[2 * H + colg];
    floatx16 acc[3][RT];
#pragma unroll
    for (int rt = 0; rt < RT; ++rt) {
#pragma unroll
      for (int e = 0; e < 16; ++e) {
        acc[0][rt][e] = bi; acc[1][rt][e] = bc; acc[2][rt][e] = bo;
      }
    }
    const unsigned short* aBase = sIn + (size_t)(rtBase + (lane & 31)) * LDSP + ((lane >> 5) << 3);
#pragma unroll 1
    for (int ks = 0; ks < nKT; ++ks) {
      int nks = (ks + 1 < nKT) ? (ks + 1) : ks;
      short8 nb0 = *(const short8*)(p0 + (size_t)nks * 512);
      short8 nb1 = *(const short8*)(p1 + (size_t)nks * 512);
      short8 nb2 = *(const short8*)(p2 + (size_t)nks * 512);
      short8 a[RT];
#pragma unroll
      for (int rt = 0; rt < RT; ++rt)
        a[rt] = *(const short8*)(aBase + (size_t)rt * 32 * LDSP + ks * 16);
#pragma unroll
      for (int rt = 0; rt < RT; ++rt) {
        acc[0][rt] = __builtin_amdgcn_mfma_f32_32x32x16_bf16(a[rt], b0, acc[0][rt], 0, 0, 0);
        acc[1][rt] = __builtin_amdgcn_mfma_f32_32x32x16_bf16(a[rt], b1, acc[1][rt], 0, 0, 0);
        acc[2][rt] = __builtin_amdgcn_mfma_f32_32x32x16_bf16(a[rt], b2, acc[2][rt], 0, 0, 0);
      }
      b0 = nb0; b1 = nb1; b2 = nb2;
    }
    float dw = 0.f;
    if constexpr (MODE == 1) dw = dotw[colg];
#pragma unroll
    for (int rt = 0; rt < RT; ++rt) {
#pragma unroll
      for (int reg = 0; reg < 16; ++reg) {
        int row = rtBase + rt * 32 + (reg & 3) + 8 * (reg >> 2) + 4 * (lane >> 5);
        float h = cell_h(acc[0][rt][reg], acc[1][rt][reg], acc[2][rt][reg]);
        if constexpr (MODE == 0) {
          // rows r and r+4 hit disjoint 16-bank halves -> conflict-free
          sOut[(size_t)row * LDSP + colg] = f2bf(h);
        } else {
          float v = fmaxf(h, 0.f) * dw;
          v += __shfl_xor(v, 1, 32);
          v += __shfl_xor(v, 2, 32);
          v += __shfl_xor(v, 4, 32);
          v += __shfl_xor(v, 8, 32);
          v += __shfl_xor(v, 16, 32);
          if ((lane & 31) == 0) atomicAdd(&accVec[row], v);
        }
      }
    }
  }
}

// 512 threads = 8 waves = 2 waves/SIMD, 1 block/CU (LDS 133.6 KB).
// waves_per_eu(2,2): 256 unified regs/wave. acc 96 AGPR + ~60 arch = fits.
// Per-ks matrix work (6 MFMA x ~32 SIMD-cyc) is large enough that 2 waves
// keep the matrix pipe fed (unlike R4's 16x16 shape).
__attribute__((amdgpu_waves_per_eu(2, 2)))
__global__ __launch_bounds__(512) void dfrnn_main(
    const float* __restrict__ X,
    const unsigned short* __restrict__ wpk,
    const float* __restrict__ fpk,
    float* __restrict__ out)
{
  __shared__ __align__(16) unsigned short bufA[64 * LDSP];
  __shared__ __align__(16) unsigned short bufB[64 * LDSP];
  __shared__ float accMu[64];
  __shared__ float accSt[64];
  int tid = threadIdx.x;
  int wave = tid >> 6, lane = tid & 63;
  size_t blkTok = (size_t)blockIdx.x * 64;

  if (tid < 64) { accMu[tid] = 0.f; accSt[tid] = 0.f; }
  // load X tile [64 x 128] fp32 -> bf16, NON-TEMPORAL (don't evict weights
  // from L2 — R8 FETCH showed weights re-fetched ~30x from HBM)
  for (int i = tid; i < 64 * 32; i += 512) {
    int row = i >> 5, c4 = i & 31;
    f4 v = __builtin_nontemporal_load((const f4*)(X + (blkTok + row) * 128 + c4 * 4));
    ushort4 b;
    b.x = f2bf(v.x); b.y = f2bf(v.y); b.z = f2bf(v.z); b.w = f2bf(v.w);
    *(ushort4*)&bufA[(size_t)row * LDSP + c4 * 4] = b;
  }
  __syncthreads();

  // noise L1: A[0..128) -> A[128..256); 8 waves: tn = wave>>1 (0..3),
  // row-tile = (wave&1)*32, RT=1 (acc 48)
  layer_run<128, 128, 1, 1, 0, 0>(bufA, bufA + 128, wpk + O_NW0, fpk + F_NB0,
                                  nullptr, nullptr, wave >> 1, (wave & 1) * 32, lane);
  __syncthreads();

  // noise L2: A[128..256) -> accSt (MODE 1); then global L1: A[0..128) -> B
  layer_run<128, 128, 1, 1, 0, 1>(bufA + 128, nullptr, wpk + O_NW1, fpk + F_NB1,
                                  fpk + F_AW, accSt, wave >> 1, (wave & 1) * 32, lane);
  layer_run<128, 512, 2, 2, 8, 0>(bufA, bufB, wpk + O_GW0, fpk + F_GB0,
                                  nullptr, nullptr, wave, 0, lane);
  __syncthreads();

  // global L2: B -> A (overwrites X + noise h, both dead)
  layer_run<512, 512, 2, 2, 8, 0>(bufB, bufA, wpk + O_GW1, fpk + F_GB1,
                                  nullptr, nullptr, wave, 0, lane);
  __syncthreads();

  // global L3: A -> accMu (relu-dot with w_e)
  layer_run<512, 512, 2, 2, 8, 1>(bufA, nullptr, wpk + O_GW2, fpk + F_GB2,
                                  fpk + F_WE, accMu, wave, 0, lane);
  __syncthreads();

  if (tid < 64) {
    float mu = accMu[tid] + fpk[F_BE];
    float st = accSt[tid] + fpk[F_AB];
    out[blkTok + tid] = mu;
    out[NTOK + blkTok + tid] = log1pf(__expf(st)) + 1e-6f;
  }
}

// ---------------- launch ----------------
extern "C" void kernel_launch(void* const* d_in, const int* in_sizes, int n_in,
                              void* d_out, int out_size, void* d_ws, size_t ws_size,
                              hipStream_t stream) {
  const float* X     = (const float*)d_in[0];
  const float* gW0   = (const float*)d_in[1];
  const float* gbi0  = (const float*)d_in[2];
  const float* gbh0  = (const float*)d_in[3];
  const float* gW    = (const float*)d_in[4];
  const float* gbi   = (const float*)d_in[5];
  const float* gbh   = (const float*)d_in[6];
  const float* eW    = (const float*)d_in[7];
  const float* eb    = (const float*)d_in[8];
  const float* nW0   = (const float*)d_in[9];
  const float* nbi0  = (const float*)d_in[10];
  const float* nbh0  = (const float*)d_in[11];
  const float* nW    = (const float*)d_in[12];
  const float* nbi   = (const float*)d_in[13];
  const float* nbh   = (const float*)d_in[14];
  const float* aW    = (const float*)d_in[15];
  const float* ab    = (const float*)d_in[16];

  unsigned short* wpk = (unsigned short*)d_ws;
  float* fpk = (float*)((char*)d_ws + NWS * 2);

  long prepTotal = NWS + 1536 * 3 + 384 * 2 + 512 + 128 + 2;
  int prepBlocks = (int)((prepTotal + 255) / 256);
  prep_kernel<<<prepBlocks, 256, 0, stream>>>(gW0, gbi0, gbh0, gW, gbi, gbh, eW, eb,
                                              nW0, nbi0, nbh0, nW, nbi, nbh, aW, ab,
                                              wpk, fpk);
  dfrnn_main<<<3072, 512, 0, stream>>>(X, wpk, fpk, (float*)d_out);
}

// Round 10
// 913.264 us; speedup vs baseline: 1.3368x; 1.3368x over previous
//
#include <hip/hip_runtime.h>

// ---------------- problem dims ----------------
#define IN_F  128
#define GHID  512
#define NHID  128
#define NTOK  196608L   // 1024 * 192
#define LDSP  520       // LDS row pitch in bf16 elems (512 + 8 pad)

#define L2E 1.4426950408889634f

typedef __attribute__((ext_vector_type(8))) short short8;
typedef __attribute__((ext_vector_type(4))) float floatx4;
typedef __attribute__((ext_vector_type(4))) float f4;

// ---------------- ws layout ----------------
// bf16 packed weights (ushort elems), 16x16x32 fragment order:
//   frag index = ((gate*(H/16) + tn) * (K/32) + tk), 512 elems per frag,
//   elem (lane,j): n = tn*16 + (lane&15), k = tk*32 + (lane>>4)*8 + j
#define O_GW0 0L
#define O_GW1 196608L
#define O_GW2 983040L
#define O_NW0 1769472L
#define O_NW1 1818624L
#define NWS   1867776L
// fp32 region (float elems), base byte = NWS*2
#define F_GB0 0
#define F_GB1 1536
#define F_GB2 3072
#define F_NB0 4608
#define F_NB1 4992
#define F_WE  5376
#define F_AW  5888
#define F_BE  6016
#define F_AB  6017

__device__ __forceinline__ unsigned short f2bf(float f) {
  unsigned int u = __float_as_uint(f);
  u += 0x7fffu + ((u >> 16) & 1u);      // RNE
  return (unsigned short)(u >> 16);
}

// ---------------- prep kernel: repack weights (NO prescale — R6 lesson) ----
__device__ __forceinline__ long srcoff(long pp, int H, int K) {
  long f = pp >> 9;
  int r = (int)(pp & 511);
  int ln = r >> 3, j = r & 7;
  int nKT = K >> 5, nCT = H >> 4;
  int tk = (int)(f % nKT);
  long t2 = f / nKT;
  int tn = (int)(t2 % nCT);
  int gate = (int)(t2 / nCT);
  int n = tn * 16 + (ln & 15);
  int k = tk * 32 + ((ln >> 4) << 3) + j;
  int go = (gate == 0) ? 0 : ((gate == 1) ? 2 * H : 3 * H);  // i, c, o rows
  return (long)(go + n) * K + k;
}

__global__ void prep_kernel(
    const float* __restrict__ gW0, const float* __restrict__ gbi0, const float* __restrict__ gbh0,
    const float* __restrict__ gW,  const float* __restrict__ gbi,  const float* __restrict__ gbh,
    const float* __restrict__ eW,  const float* __restrict__ eb,
    const float* __restrict__ nW0, const float* __restrict__ nbi0, const float* __restrict__ nbh0,
    const float* __restrict__ nW,  const float* __restrict__ nbi,  const float* __restrict__ nbh,
    const float* __restrict__ aW,  const float* __restrict__ ab,
    unsigned short* __restrict__ wpk, float* __restrict__ fpk)
{
  long idx = (long)blockIdx.x * blockDim.x + threadIdx.x;
  if (idx < NWS) {
    const float* src;
    long off;
    if (idx < O_GW1)      { off = srcoff(idx - O_GW0, 512, 128); src = gW0; }
    else if (idx < O_GW2) { off = srcoff(idx - O_GW1, 512, 512); src = gW; }
    else if (idx < O_NW0) { off = srcoff(idx - O_GW2, 512, 512); src = gW + 1048576; }
    else if (idx < O_NW1) { off = srcoff(idx - O_NW0, 128, 128); src = nW0; }
    else                  { off = srcoff(idx - O_NW1, 128, 128); src = nW; }
    wpk[idx] = f2bf(src[off]);
    return;
  }
  long p = idx - NWS;
  if (p < 1536) { int g = (int)(p >> 9), n = (int)(p & 511);
    int o = (g == 0 ? 0 : (g == 1 ? 1024 : 1536)) + n;
    fpk[F_GB0 + p] = gbi0[o] + gbh0[o]; return; }
  p -= 1536;
  if (p < 1536) { int g = (int)(p >> 9), n = (int)(p & 511);
    int o = (g == 0 ? 0 : (g == 1 ? 1024 : 1536)) + n;
    fpk[F_GB1 + p] = gbi[o] + gbh[o]; return; }
  p -= 1536;
  if (p < 1536) { int g = (int)(p >> 9), n = (int)(p & 511);
    int o = (g == 0 ? 0 : (g == 1 ? 1024 : 1536)) + n;
    fpk[F_GB2 + p] = gbi[2048 + o] + gbh[2048 + o]; return; }
  p -= 1536;
  if (p < 384) { int g = (int)(p / 128), n = (int)(p % 128);
    int o = (g == 0 ? 0 : (g == 1 ? 256 : 384)) + n;
    fpk[F_NB0 + p] = nbi0[o] + nbh0[o]; return; }
  p -= 384;
  if (p < 384) { int g = (int)(p / 128), n = (int)(p % 128);
    int o = (g == 0 ? 0 : (g == 1 ? 256 : 384)) + n;
    fpk[F_NB1 + p] = nbi[o] + nbh[o]; return; }
  p -= 384;
  if (p < 512) { float s = 0.f;
    for (int f = 0; f < 10; ++f) s += eW[f * 512 + p];
    fpk[F_WE + p] = s; return; }
  p -= 512;
  if (p < 128) { fpk[F_AW + p] = aW[p]; return; }
  p -= 128;
  if (p == 0) { float s = 0.f; for (int f = 0; f < 10; ++f) s += eb[f]; fpk[F_BE] = s; return; }
  if (p == 1) { fpk[F_AB] = ab[0]; return; }
}

// LSTM-cell combine from RAW gates (in-kernel scaling; prep stays byte-stable)
__device__ __forceinline__ float cell_h(float gi, float gc, float go) {
  float ei = __builtin_amdgcn_exp2f(gi * -L2E);
  float u  = __builtin_amdgcn_exp2f(gc * (2.0f * L2E));
  float eo = __builtin_amdgcn_exp2f(go * -L2E);
  float r1 = __builtin_amdgcn_rcpf((u + 1.f) * (1.f + ei));
  float cc = (u - 1.f) * r1;
  float s  = cc * cc;
  float num = cc * fmaf(10.f, s, 105.f);
  float den = fmaf(s, s + 45.f, 105.f);
  return num * __builtin_amdgcn_rcpf(den * (1.f + eo));
}

// ---------------- fused main kernel ----------------
// R10: OPERAND SWAP — weights are the A operand (D rows = outcols), tokens
// the B operand (D cols = tokens). Each lane then holds 4 consecutive outcols
// of one token -> h-epilogue is ONE packed ds_write_b64 (R8: 4 scalar b16
// writes at conflicting banks), bias fold becomes a float4 load, and the
// MODE-1 dot is 4 FMA + 2 shuffles + 1 atomic per lane.
// B-prefetch rotation (R8) + nt X-loads (R9) keep weight loads L2-hit.
template <int K, int H, int TT, int CPW, int NW, int MODE>
__device__ __forceinline__ void layer_run(
    const unsigned short* __restrict__ sIn,
    unsigned short* __restrict__ sOut,
    const unsigned short* __restrict__ wp,
    const float* __restrict__ bias,
    const float* __restrict__ dotw,
    float* accVec,
    int colTile0, int tokBase, int lane)
{
  constexpr int nKT = K / 32;
  constexpr int nCT = H / 16;
#pragma unroll
  for (int cp = 0; cp < CPW; ++cp) {
    int tn = colTile0 + cp * NW;
    int colBase = tn * 16 + ((lane >> 4) << 2);   // 4 consecutive outcols/lane
    const unsigned short* p0 = wp + (size_t)tn * nKT * 512 + lane * 8;
    const unsigned short* p1 = p0 + (size_t)nCT * nKT * 512;
    const unsigned short* p2 = p1 + (size_t)nCT * nKT * 512;
    short8 b0 = *(const short8*)(p0);
    short8 b1 = *(const short8*)(p1);
    short8 b2 = *(const short8*)(p2);
    f4 bi4 = *(const f4*)(bias + colBase);
    f4 bc4 = *(const f4*)(bias + H + colBase);
    f4 bo4 = *(const f4*)(bias + 2 * H + colBase);
    floatx4 acc[3][TT];
#pragma unroll
    for (int tt = 0; tt < TT; ++tt) {
      acc[0][tt] = (floatx4){bi4.x, bi4.y, bi4.z, bi4.w};
      acc[1][tt] = (floatx4){bc4.x, bc4.y, bc4.z, bc4.w};
      acc[2][tt] = (floatx4){bo4.x, bo4.y, bo4.z, bo4.w};
    }
    const unsigned short* aRow = sIn + (size_t)(tokBase + (lane & 15)) * LDSP + ((lane >> 4) << 3);
#pragma unroll 1
    for (int ks = 0; ks < nKT; ++ks) {
      int nks = (ks + 1 < nKT) ? (ks + 1) : ks;
      short8 nb0 = *(const short8*)(p0 + (size_t)nks * 512);
      short8 nb1 = *(const short8*)(p1 + (size_t)nks * 512);
      short8 nb2 = *(const short8*)(p2 + (size_t)nks * 512);
      short8 a[TT];
#pragma unroll
      for (int tt = 0; tt < TT; ++tt)
        a[tt] = *(const short8*)(aRow + (size_t)tt * 16 * LDSP + ks * 32);
#pragma unroll
      for (int tt = 0; tt < TT; ++tt) {
        // A = weights (rows -> outcols), B = tokens (cols -> tokens)
        acc[0][tt] = __builtin_amdgcn_mfma_f32_16x16x32_bf16(b0, a[tt], acc[0][tt], 0, 0, 0);
        acc[1][tt] = __builtin_amdgcn_mfma_f32_16x16x32_bf16(b1, a[tt], acc[1][tt], 0, 0, 0);
        acc[2][tt] = __builtin_amdgcn_mfma_f32_16x16x32_bf16(b2, a[tt], acc[2][tt], 0, 0, 0);
      }
      b0 = nb0; b1 = nb1; b2 = nb2;
    }
    f4 dw4;
    if constexpr (MODE == 1) dw4 = *(const f4*)(dotw + colBase);
#pragma unroll
    for (int tt = 0; tt < TT; ++tt) {
      int token = tokBase + tt * 16 + (lane & 15);
      if constexpr (MODE == 0) {
        ushort4 hw;
        hw.x = f2bf(cell_h(acc[0][tt][0], acc[1][tt][0], acc[2][tt][0]));
        hw.y = f2bf(cell_h(acc[0][tt][1], acc[1][tt][1], acc[2][tt][1]));
        hw.z = f2bf(cell_h(acc[0][tt][2], acc[1][tt][2], acc[2][tt][2]));
        hw.w = f2bf(cell_h(acc[0][tt][3], acc[1][tt][3], acc[2][tt][3]));
        // 8B packed write; banks 2-way aliased (free), no scalar writes
        *(ushort4*)&sOut[(size_t)token * LDSP + colBase] = hw;
      } else {
        float v = 0.f;
#pragma unroll
        for (int r = 0; r < 4; ++r) {
          float h = cell_h(acc[0][tt][r], acc[1][tt][r], acc[2][tt][r]);
          v = fmaf(fmaxf(h, 0.f), dw4[r], v);
        }
        v += __shfl_xor(v, 16);
        v += __shfl_xor(v, 32);
        if (lane < 16) atomicAdd(&accVec[token], v);
      }
    }
  }
}

// 1024 threads = 16 waves = 4 waves/SIMD, 1 block/CU (LDS 133.6 KB).
// waves_per_eu(4,4): 128 unified regs/wave (~52 arch + 48 acc measured R8).
__attribute__((amdgpu_waves_per_eu(4, 4)))
__global__ __launch_bounds__(1024) void dfrnn_main(
    const float* __restrict__ X,
    const unsigned short* __restrict__ wpk,
    const float* __restrict__ fpk,
    float* __restrict__ out)
{
  __shared__ __align__(16) unsigned short bufA[64 * LDSP];
  __shared__ __align__(16) unsigned short bufB[64 * LDSP];
  __shared__ float accMu[64];
  __shared__ float accSt[64];
  int tid = threadIdx.x;
  int wave = tid >> 6, lane = tid & 63;
  size_t blkTok = (size_t)blockIdx.x * 64;

  if (tid < 64) { accMu[tid] = 0.f; accSt[tid] = 0.f; }
  // load X tile [64 x 128] fp32 -> bf16, NON-TEMPORAL so streaming X doesn't
  // evict weights from L2 (R9 evidence: FETCH 224 -> 72 MB)
  for (int i = tid; i < 64 * 32; i += 1024) {
    int row = i >> 5, c4 = i & 31;
    f4 v = __builtin_nontemporal_load((const f4*)(X + (blkTok + row) * 128 + c4 * 4));
    ushort4 b;
    b.x = f2bf(v.x); b.y = f2bf(v.y); b.z = f2bf(v.z); b.w = f2bf(v.w);
    *(ushort4*)&bufA[(size_t)row * LDSP + c4 * 4] = b;
  }
  __syncthreads();

  // noise L1: A[0..128) -> A[128..256)  (disjoint cols, safe in-flight)
  // 16 waves: col tile = wave&7, token half = (wave>>3)*32, TT=2
  layer_run<128, 128, 2, 1, 8, 0>(bufA, bufA + 128, wpk + O_NW0, fpk + F_NB0,
                                  nullptr, nullptr, wave & 7, (wave >> 3) * 32, lane);
  __syncthreads();

  // noise L2: A[128..256) -> accSt (MODE 1); then global L1: A[0..128) -> B
  layer_run<128, 128, 2, 1, 8, 1>(bufA + 128, nullptr, wpk + O_NW1, fpk + F_NB1,
                                  fpk + F_AW, accSt, wave & 7, (wave >> 3) * 32, lane);
  layer_run<128, 512, 4, 2, 16, 0>(bufA, bufB, wpk + O_GW0, fpk + F_GB0,
                                   nullptr, nullptr, wave, 0, lane);
  __syncthreads();

  // global L2: B -> A (overwrites X + noise h, both dead)
  layer_run<512, 512, 4, 2, 16, 0>(bufB, bufA, wpk + O_GW1, fpk + F_GB1,
                                   nullptr, nullptr, wave, 0, lane);
  __syncthreads();

  // global L3: A -> accMu (relu-dot with w_e)
  layer_run<512, 512, 4, 2, 16, 1>(bufA, nullptr, wpk + O_GW2, fpk + F_GB2,
                                   fpk + F_WE, accMu, wave, 0, lane);
  __syncthreads();

  if (tid < 64) {
    float mu = accMu[tid] + fpk[F_BE];
    float st = accSt[tid] + fpk[F_AB];
    out[blkTok + tid] = mu;
    out[NTOK + blkTok + tid] = log1pf(__expf(st)) + 1e-6f;
  }
}

// ---------------- launch ----------------
extern "C" void kernel_launch(void* const* d_in, const int* in_sizes, int n_in,
                              void* d_out, int out_size, void* d_ws, size_t ws_size,
                              hipStream_t stream) {
  const float* X     = (const float*)d_in[0];
  const float* gW0   = (const float*)d_in[1];
  const float* gbi0  = (const float*)d_in[2];
  const float* gbh0  = (const float*)d_in[3];
  const float* gW    = (const float*)d_in[4];
  const float* gbi   = (const float*)d_in[5];
  const float* gbh   = (const float*)d_in[6];
  const float* eW    = (const float*)d_in[7];
  const float* eb    = (const float*)d_in[8];
  const float* nW0   = (const float*)d_in[9];
  const float* nbi0  = (const float*)d_in[10];
  const float* nbh0  = (const float*)d_in[11];
  const float* nW    = (const float*)d_in[12];
  const float* nbi   = (const float*)d_in[13];
  const float* nbh   = (const float*)d_in[14];
  const float* aW    = (const float*)d_in[15];
  const float* ab    = (const float*)d_in[16];

  unsigned short* wpk = (unsigned short*)d_ws;
  float* fpk = (float*)((char*)d_ws + NWS * 2);

  long prepTotal = NWS + 1536 * 3 + 384 * 2 + 512 + 128 + 2;
  int prepBlocks = (int)((prepTotal + 255) / 256);
  prep_kernel<<<prepBlocks, 256, 0, stream>>>(gW0, gbi0, gbh0, gW, gbi, gbh, eW, eb,
                                              nW0, nbi0, nbh0, nW, nbi, nbh, aW, ab,
                                              wpk, fpk);
  dfrnn_main<<<3072, 1024, 0, stream>>>(X, wpk, fpk, (float*)d_out);
}